// Round 18
// baseline (504.893 us; speedup 1.0000x reference)
//
#include <hip/hip_runtime.h>
#include <hip/hip_fp16.h>

#define NUM_USERS 200000
#define NUM_ITEMS 100000
#define DIM 64
#define NUM_EDGES 2000000
#define BATCH 16384
#define NUM_LAYERS 3

#define NU64 ((size_t)NUM_USERS * DIM)
#define NI64 ((size_t)NUM_ITEMS * DIM)

// bucketed CSR: user buckets = 2048-node ranges, item buckets = 1024-node ranges
#define RU_SHIFT 11
#define RI_SHIFT 10
#define NBU 98   // ceil(200000 / 2048)
#define NBI 98   // ceil(100000 / 1024)
#define CAPU 24576  // fixed capacity per bucket (expected ~20480, 28-sigma margin)
#define CAPI 24576
#define EPB 1024    // edges per scatter block
#define VMASK 0x3FFFF  // 18-bit neighbor id (max 200000 < 262144)

// ---------------- init (fp16 table copies) ----------------

__global__ void convert_kernel(const float4* __restrict__ ut, const float4* __restrict__ it,
                               uint2* __restrict__ uH, uint2* __restrict__ iH) {
    int idx = blockIdx.x * blockDim.x + threadIdx.x;
    const int n4u = (int)(NU64 / 4), n4i = (int)(NI64 / 4);
    if (idx < n4u) {
        float4 v = ut[idx];
        __half2 h0 = __floats2half2_rn(v.x, v.y);
        __half2 h1 = __floats2half2_rn(v.z, v.w);
        uint2 p; p.x = *(unsigned*)&h0; p.y = *(unsigned*)&h1;
        uH[idx] = p;
    } else if (idx < n4u + n4i) {
        int k = idx - n4u;
        float4 v = it[k];
        __half2 h0 = __floats2half2_rn(v.x, v.y);
        __half2 h1 = __floats2half2_rn(v.z, v.w);
        uint2 p; p.x = *(unsigned*)&h0; p.y = *(unsigned*)&h1;
        iH[k] = p;
    }
}

// ---------------- final dot: gather table + 3 layer embs at sampled rows ----------------

__global__ void final_dot_kernel(const float* __restrict__ uT, const float* __restrict__ iT,
                                 const __half* __restrict__ uE1, const __half* __restrict__ uE2,
                                 const __half* __restrict__ uE3,
                                 const __half* __restrict__ iE1, const __half* __restrict__ iE2,
                                 const __half* __restrict__ iE3,
                                 const int* __restrict__ u_idx, const int* __restrict__ i_idx,
                                 float* __restrict__ out) {
    int b    = (blockIdx.x * blockDim.x + threadIdx.x) >> 6;
    int lane = threadIdx.x & 63;
    if (b >= BATCH) return;
    int u = u_idx[b];
    int i = i_idx[b];
    size_t uo = (size_t)u * DIM + lane;
    size_t io = (size_t)i * DIM + lane;
    float su = uT[uo] + __half2float(uE1[uo]) + __half2float(uE2[uo]) + __half2float(uE3[uo]);
    float si = iT[io] + __half2float(iE1[io]) + __half2float(iE2[io]) + __half2float(iE3[io]);
    float p = su * si;
    #pragma unroll
    for (int o = 32; o > 0; o >>= 1) p += __shfl_xor(p, o, 64);
    if (lane == 0) out[b] = p * (1.0f / ((NUM_LAYERS + 1) * (NUM_LAYERS + 1)));
}

// ---------------- CSR construction v3 (packed 4B staging records) ----------------

// Pass A: per-wave-replicated LDS binning, fixed-capacity per-bucket staging.
// Record = (node_offset_in_bucket << 18) | neighbor_id.
__global__ void bucket_scatter(const int* __restrict__ un, const int* __restrict__ in_,
                               int* __restrict__ gcurU, int* __restrict__ gcurI,
                               unsigned* __restrict__ stageU, unsigned* __restrict__ stageI) {
    __shared__ int cntU[4][NBU], cntI[4][NBI];
    __shared__ int baseU[4][NBU], baseI[4][NBI];
    int t = threadIdx.x;
    int w = t >> 6;  // wave 0..3
    for (int k = t; k < 4 * NBU; k += 256) ((int*)cntU)[k] = 0;
    for (int k = t; k < 4 * NBI; k += 256) ((int*)cntI)[k] = 0;
    __syncthreads();
    int e0 = blockIdx.x * EPB + t;
    int u[4], it[4], bu[4], bi[4], ru[4], ri[4];
    bool valid[4];
    #pragma unroll
    for (int k = 0; k < 4; ++k) {
        int e = e0 + k * 256;
        valid[k] = (e < NUM_EDGES);
        if (valid[k]) {
            u[k]  = un[e];
            it[k] = in_[e];
            bu[k] = u[k]  >> RU_SHIFT;
            bi[k] = it[k] >> RI_SHIFT;
            ru[k] = atomicAdd(&cntU[w][bu[k]], 1);
            ri[k] = atomicAdd(&cntI[w][bi[k]], 1);
        }
    }
    __syncthreads();
    if (t < NBU) {
        int c0 = cntU[0][t], c1 = cntU[1][t], c2 = cntU[2][t], c3 = cntU[3][t];
        int b = t * CAPU + atomicAdd(&gcurU[t], c0 + c1 + c2 + c3);
        baseU[0][t] = b; baseU[1][t] = b + c0; baseU[2][t] = b + c0 + c1; baseU[3][t] = b + c0 + c1 + c2;
    }
    if (t < NBI) {
        int c0 = cntI[0][t], c1 = cntI[1][t], c2 = cntI[2][t], c3 = cntI[3][t];
        int b = t * CAPI + atomicAdd(&gcurI[t], c0 + c1 + c2 + c3);
        baseI[0][t] = b; baseI[1][t] = b + c0; baseI[2][t] = b + c0 + c1; baseI[3][t] = b + c0 + c1 + c2;
    }
    __syncthreads();
    #pragma unroll
    for (int k = 0; k < 4; ++k) {
        if (valid[k]) {
            stageU[baseU[w][bu[k]] + ru[k]] = ((unsigned)(u[k]  & ((1 << RU_SHIFT) - 1)) << 18) | (unsigned)it[k];
            stageI[baseI[w][bi[k]] + ri[k]] = ((unsigned)(it[k] & ((1 << RI_SHIFT) - 1)) << 18) | (unsigned)u[k];
        }
    }
}

// Pass B: one block per bucket. Per-node counts + LDS prefix scan produce
// offs/deg locally, then place records with LDS cursors.
__global__ void bucket_place(const int* __restrict__ gcurU, const int* __restrict__ gcurI,
                             const unsigned* __restrict__ stageU, const unsigned* __restrict__ stageI,
                             int* __restrict__ u_offs, int* __restrict__ i_offs,
                             int* __restrict__ u_deg, int* __restrict__ i_deg,
                             int* __restrict__ u_adj, int* __restrict__ i_adj) {
    __shared__ int cnt[2048];
    __shared__ int offs_l[2048];
    __shared__ int wsum[1024];
    int b = blockIdx.x, t = threadIdx.x;
    const unsigned* stage; int* adj; int* offs; int* deg; int lo, range, nrec, bbase;
    if (b < NBU) {
        stage = stageU + (size_t)b * CAPU; adj = u_adj; offs = u_offs; deg = u_deg;
        nrec = gcurU[b]; lo = b << RU_SHIFT; bbase = b * CAPU;
        range = NUM_USERS - lo; if (range > 2048) range = 2048;
    } else {
        int bb = b - NBU;
        stage = stageI + (size_t)bb * CAPI; adj = i_adj; offs = i_offs; deg = i_deg;
        nrec = gcurI[bb]; lo = bb << RI_SHIFT; bbase = bb * CAPI;
        range = NUM_ITEMS - lo; if (range > 1024) range = 1024;
    }
    cnt[t] = 0; cnt[t + 1024] = 0;
    __syncthreads();
    for (int r = t; r < nrec; r += 1024) atomicAdd(&cnt[stage[r] >> 18], 1);
    __syncthreads();
    int c0 = cnt[2 * t], c1 = cnt[2 * t + 1];
    int s = c0 + c1;
    wsum[t] = s;
    __syncthreads();
    for (int off = 1; off < 1024; off <<= 1) {
        int v = (t >= off) ? wsum[t - off] : 0;
        __syncthreads();
        wsum[t] += v;
        __syncthreads();
    }
    int excl = wsum[t] - s;  // exclusive prefix of node 2t
    offs_l[2 * t] = excl;
    offs_l[2 * t + 1] = excl + c0;
    if (2 * t < range)     { offs[lo + 2 * t]     = bbase + excl;      deg[lo + 2 * t]     = c0; }
    if (2 * t + 1 < range) { offs[lo + 2 * t + 1] = bbase + excl + c0; deg[lo + 2 * t + 1] = c1; }
    cnt[2 * t] = 0; cnt[2 * t + 1] = 0;   // reuse as placement cursors
    __syncthreads();
    for (int r = t; r < nrec; r += 1024) {
        unsigned rec = stage[r];
        int loc = (int)(rec >> 18);
        int p = atomicAdd(&cnt[loc], 1);
        adj[bbase + offs_l[loc] + p] = (int)(rec & VMASK);
    }
}

// ---------------- fused pull + normalize (float2 half-split, fp16 packed accumulate) ----------------
// One wave per row; lanes 0-31 process neighbor j, lanes 32-63 neighbor j+1,
// each lane loads __half2 (4B) = 2 dims. Accumulate with v_pk_add_f16 into two
// interleaved half2 accumulators (dep-chain break); convert to f32 only for the
// norm reduction and final write.
__global__ void pull_norm_kernel(const int* __restrict__ u_offs, const int* __restrict__ u_deg,
                                 const int* __restrict__ u_adj,
                                 const int* __restrict__ i_offs, const int* __restrict__ i_deg,
                                 const int* __restrict__ i_adj,
                                 const __half* __restrict__ uprev, const __half* __restrict__ iprev,
                                 __half* __restrict__ unew, __half* __restrict__ inew) {
    int w    = (blockIdx.x * blockDim.x + threadIdx.x) >> 6;
    int lane = threadIdx.x & 63;
    int half = lane >> 5;   // 0 or 1
    int l32  = lane & 31;
    const int* offs; const int* deg; const int* adj; const __half* src; __half* demb; int row;
    if (w < NUM_USERS) {
        row = w; offs = u_offs; deg = u_deg; adj = u_adj; src = iprev; demb = unew;
    } else {
        row = w - NUM_USERS;
        if (row >= NUM_ITEMS) return;
        offs = i_offs; deg = i_deg; adj = i_adj; src = uprev; demb = inew;
    }
    int start = offs[row];
    int cnt   = deg[row];
    __half2 acc0 = __floats2half2_rn(0.0f, 0.0f);
    __half2 acc1 = __floats2half2_rn(0.0f, 0.0f);
    for (int base = 0; base < cnt; base += 64) {
        int rem = cnt - base;
        if (rem > 64) rem = 64;
        int idx = (lane < rem) ? adj[start + base + lane] : 0;
        int j = 0;
        // 8 pairs (16 neighbors) per unrolled iteration: 8 independent 256B loads in flight
        for (; j + 16 <= rem; j += 16) {
            #pragma unroll
            for (int p = 0; p < 8; ++p) {
                int nb = __shfl(idx, j + 2 * p + half, 64);
                __half2 v = ((const __half2*)(src + (size_t)nb * DIM))[l32];
                if (p & 1) acc1 = __hadd2(acc1, v);
                else       acc0 = __hadd2(acc0, v);
            }
        }
        // 4 pairs (8 neighbors)
        for (; j + 8 <= rem; j += 8) {
            #pragma unroll
            for (int p = 0; p < 4; ++p) {
                int nb = __shfl(idx, j + 2 * p + half, 64);
                __half2 v = ((const __half2*)(src + (size_t)nb * DIM))[l32];
                if (p & 1) acc1 = __hadd2(acc1, v);
                else       acc0 = __hadd2(acc0, v);
            }
        }
        for (; j + 2 <= rem; j += 2) {
            int nb = __shfl(idx, j + half, 64);
            __half2 v = ((const __half2*)(src + (size_t)nb * DIM))[l32];
            acc0 = __hadd2(acc0, v);
        }
        if (j < rem) {  // odd leftover neighbor: lanes 0-31 only
            int nb = __shfl(idx, j, 64);
            __half2 v = ((const __half2*)(src + (size_t)nb * DIM))[l32];
            if (half == 0) acc1 = __hadd2(acc1, v);
        }
    }
    // upconvert and merge the two half-wave partial sums in f32
    float2 f0 = __half22float2(acc0);
    float2 f1 = __half22float2(acc1);
    float ax = f0.x + f1.x;
    float ay = f0.y + f1.y;
    ax += __shfl_xor(ax, 32, 64);
    ay += __shfl_xor(ay, 32, 64);
    float ss = ax * ax + ay * ay;
    #pragma unroll
    for (int o = 16; o > 0; o >>= 1) ss += __shfl_xor(ss, o, 64);
    float inv = 1.0f / fmaxf(sqrtf(ss), 1e-12f);
    float nx = ax * inv, ny = ay * inv;
    if (half == 0) {
        ((__half2*)(demb + (size_t)row * DIM))[l32] = __floats2half2_rn(nx, ny);
    }
}

// ---------------- launch ----------------

extern "C" void kernel_launch(void* const* d_in, const int* in_sizes, int n_in,
                              void* d_out, int out_size, void* d_ws, size_t ws_size,
                              hipStream_t stream) {
    const float* user_table = (const float*)d_in[0];
    const float* item_table = (const float*)d_in[1];
    const int*   u_idx      = (const int*)d_in[2];
    const int*   i_idx      = (const int*)d_in[3];
    const int*   edges      = (const int*)d_in[4];
    const int*   u_nodes    = edges;              // edge_index[0]
    const int*   i_nodes    = edges + NUM_EDGES;  // edge_index[1]
    float*       out        = (float*)d_out;

    // ---- workspace layout (~130 MB) ----
    __half* uH0 = (__half*)d_ws;        // fp16 table copy (25.6 MB)
    __half* uE1 = uH0 + NU64;           // layer-1 user emb
    __half* uE2 = uE1 + NU64;           // layer-2
    __half* uE3 = uE2 + NU64;           // layer-3
    __half* iH0 = uE3 + NU64;           // fp16 item table copy (12.8 MB)
    __half* iE1 = iH0 + NI64;
    __half* iE2 = iE1 + NI64;
    __half* iE3 = iE2 + NI64;

    int* ip     = (int*)(iE3 + NI64);
    int* u_offs = ip;                        // NUM_USERS
    int* i_offs = u_offs + NUM_USERS;        // NUM_ITEMS
    int* u_deg  = i_offs + NUM_ITEMS;        // NUM_USERS
    int* i_deg  = u_deg + NUM_USERS;         // NUM_ITEMS
    int* u_adj  = i_deg + NUM_ITEMS;         // NBU*CAPU (9.6 MB)
    int* i_adj  = u_adj + (size_t)NBU * CAPU;  // NBI*CAPI (9.6 MB)
    int* gcurU  = i_adj + (size_t)NBI * CAPI;  // NBU
    int* gcurI  = gcurU + NBU;               // NBI
    unsigned* stageU = (unsigned*)(gcurI + NBI);      // NBU*CAPU u32 (9.6 MB)
    unsigned* stageI = stageU + (size_t)NBU * CAPU;   // NBI*CAPI u32 (9.6 MB)

    // ---- init: fp16 copies of the tables ----
    {
        int n4 = (int)((NU64 + NI64) / 4);
        convert_kernel<<<(n4 + 255) / 256, 256, 0, stream>>>(
            (const float4*)user_table, (const float4*)item_table,
            (uint2*)uH0, (uint2*)iH0);
    }

    // ---- CSR build v3 ----
    hipMemsetAsync(gcurU, 0, (NBU + NBI) * sizeof(int), stream);

    int nblkA = (NUM_EDGES + EPB - 1) / EPB;
    bucket_scatter<<<nblkA, 256, 0, stream>>>(u_nodes, i_nodes, gcurU, gcurI, stageU, stageI);
    bucket_place<<<NBU + NBI, 1024, 0, stream>>>(gcurU, gcurI, stageU, stageI,
                                                 u_offs, i_offs, u_deg, i_deg, u_adj, i_adj);

    // ---- 3 fused pull layers (fp16 gathers; each layer's emb persisted) ----
    long long waves = (long long)(NUM_USERS + NUM_ITEMS);
    int blocks = (int)((waves * 64 + 255) / 256);
    const __half* uprevs[3] = {uH0, uE1, uE2};
    const __half* iprevs[3] = {iH0, iE1, iE2};
    __half* udsts[3] = {uE1, uE2, uE3};
    __half* idsts[3] = {iE1, iE2, iE3};
    for (int l = 0; l < NUM_LAYERS; ++l) {
        pull_norm_kernel<<<blocks, 256, 0, stream>>>(u_offs, u_deg, u_adj,
                                                     i_offs, i_deg, i_adj,
                                                     uprevs[l], iprevs[l],
                                                     udsts[l], idsts[l]);
    }

    // ---- final dot over sampled rows: (table + e1 + e2 + e3) . (table + e1 + e2 + e3) / 16 ----
    {
        long long tb = (long long)BATCH * 64;
        final_dot_kernel<<<(int)((tb + 255) / 256), 256, 0, stream>>>(
            user_table, item_table, uE1, uE2, uE3, iE1, iE2, iE3, u_idx, i_idx, out);
    }
}

// Round 19
// 471.606 us; speedup vs baseline: 1.0706x; 1.0706x over previous
//
#include <hip/hip_runtime.h>
#include <hip/hip_fp16.h>

#define NUM_USERS 200000
#define NUM_ITEMS 100000
#define DIM 64
#define NUM_EDGES 2000000
#define BATCH 16384
#define NUM_LAYERS 3

#define NU64 ((size_t)NUM_USERS * DIM)
#define NI64 ((size_t)NUM_ITEMS * DIM)

// bucketed CSR: user buckets = 2048-node ranges, item buckets = 1024-node ranges
#define RU_SHIFT 11
#define RI_SHIFT 10
#define NBU 98   // ceil(200000 / 2048)
#define NBI 98   // ceil(100000 / 1024)
#define CAPU 24576  // fixed capacity per bucket (expected ~20480, 28-sigma margin)
#define CAPI 24576
#define EPB 1024    // edges per scatter block
#define VMASK 0x3FFFF  // 18-bit neighbor id (max 200000 < 262144)

// ---------------- init (fp16 table copies) ----------------

__global__ void convert_kernel(const float4* __restrict__ ut, const float4* __restrict__ it,
                               uint2* __restrict__ uH, uint2* __restrict__ iH) {
    int idx = blockIdx.x * blockDim.x + threadIdx.x;
    const int n4u = (int)(NU64 / 4), n4i = (int)(NI64 / 4);
    if (idx < n4u) {
        float4 v = ut[idx];
        __half2 h0 = __floats2half2_rn(v.x, v.y);
        __half2 h1 = __floats2half2_rn(v.z, v.w);
        uint2 p; p.x = *(unsigned*)&h0; p.y = *(unsigned*)&h1;
        uH[idx] = p;
    } else if (idx < n4u + n4i) {
        int k = idx - n4u;
        float4 v = it[k];
        __half2 h0 = __floats2half2_rn(v.x, v.y);
        __half2 h1 = __floats2half2_rn(v.z, v.w);
        uint2 p; p.x = *(unsigned*)&h0; p.y = *(unsigned*)&h1;
        iH[k] = p;
    }
}

// ---------------- final dot: gather table + 3 layer embs at sampled rows ----------------

__global__ void final_dot_kernel(const float* __restrict__ uT, const float* __restrict__ iT,
                                 const __half* __restrict__ uE1, const __half* __restrict__ uE2,
                                 const __half* __restrict__ uE3,
                                 const __half* __restrict__ iE1, const __half* __restrict__ iE2,
                                 const __half* __restrict__ iE3,
                                 const int* __restrict__ u_idx, const int* __restrict__ i_idx,
                                 float* __restrict__ out) {
    int b    = (blockIdx.x * blockDim.x + threadIdx.x) >> 6;
    int lane = threadIdx.x & 63;
    if (b >= BATCH) return;
    int u = u_idx[b];
    int i = i_idx[b];
    size_t uo = (size_t)u * DIM + lane;
    size_t io = (size_t)i * DIM + lane;
    float su = uT[uo] + __half2float(uE1[uo]) + __half2float(uE2[uo]) + __half2float(uE3[uo]);
    float si = iT[io] + __half2float(iE1[io]) + __half2float(iE2[io]) + __half2float(iE3[io]);
    float p = su * si;
    #pragma unroll
    for (int o = 32; o > 0; o >>= 1) p += __shfl_xor(p, o, 64);
    if (lane == 0) out[b] = p * (1.0f / ((NUM_LAYERS + 1) * (NUM_LAYERS + 1)));
}

// ---------------- CSR construction v3 (packed 4B staging records) ----------------

// Pass A: per-wave-replicated LDS binning, fixed-capacity per-bucket staging.
// Record = (node_offset_in_bucket << 18) | neighbor_id.
__global__ void bucket_scatter(const int* __restrict__ un, const int* __restrict__ in_,
                               int* __restrict__ gcurU, int* __restrict__ gcurI,
                               unsigned* __restrict__ stageU, unsigned* __restrict__ stageI) {
    __shared__ int cntU[4][NBU], cntI[4][NBI];
    __shared__ int baseU[4][NBU], baseI[4][NBI];
    int t = threadIdx.x;
    int w = t >> 6;  // wave 0..3
    for (int k = t; k < 4 * NBU; k += 256) ((int*)cntU)[k] = 0;
    for (int k = t; k < 4 * NBI; k += 256) ((int*)cntI)[k] = 0;
    __syncthreads();
    int e0 = blockIdx.x * EPB + t;
    int u[4], it[4], bu[4], bi[4], ru[4], ri[4];
    bool valid[4];
    #pragma unroll
    for (int k = 0; k < 4; ++k) {
        int e = e0 + k * 256;
        valid[k] = (e < NUM_EDGES);
        if (valid[k]) {
            u[k]  = un[e];
            it[k] = in_[e];
            bu[k] = u[k]  >> RU_SHIFT;
            bi[k] = it[k] >> RI_SHIFT;
            ru[k] = atomicAdd(&cntU[w][bu[k]], 1);
            ri[k] = atomicAdd(&cntI[w][bi[k]], 1);
        }
    }
    __syncthreads();
    if (t < NBU) {
        int c0 = cntU[0][t], c1 = cntU[1][t], c2 = cntU[2][t], c3 = cntU[3][t];
        int b = t * CAPU + atomicAdd(&gcurU[t], c0 + c1 + c2 + c3);
        baseU[0][t] = b; baseU[1][t] = b + c0; baseU[2][t] = b + c0 + c1; baseU[3][t] = b + c0 + c1 + c2;
    }
    if (t < NBI) {
        int c0 = cntI[0][t], c1 = cntI[1][t], c2 = cntI[2][t], c3 = cntI[3][t];
        int b = t * CAPI + atomicAdd(&gcurI[t], c0 + c1 + c2 + c3);
        baseI[0][t] = b; baseI[1][t] = b + c0; baseI[2][t] = b + c0 + c1; baseI[3][t] = b + c0 + c1 + c2;
    }
    __syncthreads();
    #pragma unroll
    for (int k = 0; k < 4; ++k) {
        if (valid[k]) {
            stageU[baseU[w][bu[k]] + ru[k]] = ((unsigned)(u[k]  & ((1 << RU_SHIFT) - 1)) << 18) | (unsigned)it[k];
            stageI[baseI[w][bi[k]] + ri[k]] = ((unsigned)(it[k] & ((1 << RI_SHIFT) - 1)) << 18) | (unsigned)u[k];
        }
    }
}

// Pass B: one block per bucket. Per-node counts + LDS prefix scan produce
// offs/deg locally, then place records with LDS cursors.
__global__ void bucket_place(const int* __restrict__ gcurU, const int* __restrict__ gcurI,
                             const unsigned* __restrict__ stageU, const unsigned* __restrict__ stageI,
                             int* __restrict__ u_offs, int* __restrict__ i_offs,
                             int* __restrict__ u_deg, int* __restrict__ i_deg,
                             int* __restrict__ u_adj, int* __restrict__ i_adj) {
    __shared__ int cnt[2048];
    __shared__ int offs_l[2048];
    __shared__ int wsum[1024];
    int b = blockIdx.x, t = threadIdx.x;
    const unsigned* stage; int* adj; int* offs; int* deg; int lo, range, nrec, bbase;
    if (b < NBU) {
        stage = stageU + (size_t)b * CAPU; adj = u_adj; offs = u_offs; deg = u_deg;
        nrec = gcurU[b]; lo = b << RU_SHIFT; bbase = b * CAPU;
        range = NUM_USERS - lo; if (range > 2048) range = 2048;
    } else {
        int bb = b - NBU;
        stage = stageI + (size_t)bb * CAPI; adj = i_adj; offs = i_offs; deg = i_deg;
        nrec = gcurI[bb]; lo = bb << RI_SHIFT; bbase = bb * CAPI;
        range = NUM_ITEMS - lo; if (range > 1024) range = 1024;
    }
    cnt[t] = 0; cnt[t + 1024] = 0;
    __syncthreads();
    for (int r = t; r < nrec; r += 1024) atomicAdd(&cnt[stage[r] >> 18], 1);
    __syncthreads();
    int c0 = cnt[2 * t], c1 = cnt[2 * t + 1];
    int s = c0 + c1;
    wsum[t] = s;
    __syncthreads();
    for (int off = 1; off < 1024; off <<= 1) {
        int v = (t >= off) ? wsum[t - off] : 0;
        __syncthreads();
        wsum[t] += v;
        __syncthreads();
    }
    int excl = wsum[t] - s;  // exclusive prefix of node 2t
    offs_l[2 * t] = excl;
    offs_l[2 * t + 1] = excl + c0;
    if (2 * t < range)     { offs[lo + 2 * t]     = bbase + excl;      deg[lo + 2 * t]     = c0; }
    if (2 * t + 1 < range) { offs[lo + 2 * t + 1] = bbase + excl + c0; deg[lo + 2 * t + 1] = c1; }
    cnt[2 * t] = 0; cnt[2 * t + 1] = 0;   // reuse as placement cursors
    __syncthreads();
    for (int r = t; r < nrec; r += 1024) {
        unsigned rec = stage[r];
        int loc = (int)(rec >> 18);
        int p = atomicAdd(&cnt[loc], 1);
        adj[bbase + offs_l[loc] + p] = (int)(rec & VMASK);
    }
}

// ---------------- fused pull + normalize (8x8 sub-group, uint4 loads) ----------------
// Wave = 8 subs x 8 lanes; sub s handles neighbor j+s; lane loads uint4 = 8 fp16
// dims [8*l8, 8*l8+8). fp16 packed accumulate (2 banks); shfl/load NEVER inside
// divergent branches (tail: unconditional shfl+load, predicated add; lanes >= rem
// hold idx=0 -> harmless row-0 load). f32 norm reduction; fp16 write.
__global__ void pull_norm_kernel(const int* __restrict__ u_offs, const int* __restrict__ u_deg,
                                 const int* __restrict__ u_adj,
                                 const int* __restrict__ i_offs, const int* __restrict__ i_deg,
                                 const int* __restrict__ i_adj,
                                 const __half* __restrict__ uprev, const __half* __restrict__ iprev,
                                 __half* __restrict__ unew, __half* __restrict__ inew) {
    int w    = (blockIdx.x * blockDim.x + threadIdx.x) >> 6;
    int lane = threadIdx.x & 63;
    int sub  = lane >> 3;   // 0..7
    int l8   = lane & 7;    // dims [8*l8, 8*l8+8)
    const int* offs; const int* deg; const int* adj; const __half* src; __half* demb; int row;
    if (w < NUM_USERS) {
        row = w; offs = u_offs; deg = u_deg; adj = u_adj; src = iprev; demb = unew;
    } else {
        row = w - NUM_USERS;
        if (row >= NUM_ITEMS) return;
        offs = i_offs; deg = i_deg; adj = i_adj; src = uprev; demb = inew;
    }
    int start = offs[row];
    int cnt   = deg[row];
    __half2 z = __floats2half2_rn(0.0f, 0.0f);
    __half2 aA0 = z, aA1 = z, aA2 = z, aA3 = z;   // bank A
    __half2 aB0 = z, aB1 = z, aB2 = z, aB3 = z;   // bank B
    for (int base = 0; base < cnt; base += 64) {
        int rem = cnt - base;
        if (rem > 64) rem = 64;
        int idx = (lane < rem) ? adj[start + base + lane] : 0;
        int j = 0;
        // 16 neighbors per iter: 2 independent 16B loads per lane
        for (; j + 16 <= rem; j += 16) {
            int nbA = __shfl(idx, j + sub, 64);
            int nbB = __shfl(idx, j + 8 + sub, 64);
            uint4 vA = *(const uint4*)(src + (size_t)nbA * DIM + l8 * 8);
            uint4 vB = *(const uint4*)(src + (size_t)nbB * DIM + l8 * 8);
            aA0 = __hadd2(aA0, *(const __half2*)&vA.x);
            aA1 = __hadd2(aA1, *(const __half2*)&vA.y);
            aA2 = __hadd2(aA2, *(const __half2*)&vA.z);
            aA3 = __hadd2(aA3, *(const __half2*)&vA.w);
            aB0 = __hadd2(aB0, *(const __half2*)&vB.x);
            aB1 = __hadd2(aB1, *(const __half2*)&vB.y);
            aB2 = __hadd2(aB2, *(const __half2*)&vB.z);
            aB3 = __hadd2(aB3, *(const __half2*)&vB.w);
        }
        // tail rounds of 8: shfl+load unconditional, adds predicated
        for (; j < rem; j += 8) {
            int jj = j + sub;                 // <= 63 always (j <= 56, sub <= 7)
            int nb = __shfl(idx, jj, 64);     // idx[jj] == 0 for jj >= rem (safe row 0)
            uint4 v = *(const uint4*)(src + (size_t)nb * DIM + l8 * 8);
            if (jj < rem) {
                aA0 = __hadd2(aA0, *(const __half2*)&v.x);
                aA1 = __hadd2(aA1, *(const __half2*)&v.y);
                aA2 = __hadd2(aA2, *(const __half2*)&v.z);
                aA3 = __hadd2(aA3, *(const __half2*)&v.w);
            }
        }
    }
    // merge banks
    aA0 = __hadd2(aA0, aB0);
    aA1 = __hadd2(aA1, aB1);
    aA2 = __hadd2(aA2, aB2);
    aA3 = __hadd2(aA3, aB3);
    // merge the 8 sub partials (lanes differing in bits 3,4,5 hold same dims)
    #pragma unroll
    for (int o = 8; o <= 32; o <<= 1) {
        int t0 = __shfl_xor(*(int*)&aA0, o, 64);
        int t1 = __shfl_xor(*(int*)&aA1, o, 64);
        int t2 = __shfl_xor(*(int*)&aA2, o, 64);
        int t3 = __shfl_xor(*(int*)&aA3, o, 64);
        aA0 = __hadd2(aA0, *(__half2*)&t0);
        aA1 = __hadd2(aA1, *(__half2*)&t1);
        aA2 = __hadd2(aA2, *(__half2*)&t2);
        aA3 = __hadd2(aA3, *(__half2*)&t3);
    }
    // f32 norm over the wave's 64 dims
    float2 f0 = __half22float2(aA0);
    float2 f1 = __half22float2(aA1);
    float2 f2 = __half22float2(aA2);
    float2 f3 = __half22float2(aA3);
    float ss = f0.x * f0.x + f0.y * f0.y + f1.x * f1.x + f1.y * f1.y
             + f2.x * f2.x + f2.y * f2.y + f3.x * f3.x + f3.y * f3.y;
    #pragma unroll
    for (int o = 4; o > 0; o >>= 1) ss += __shfl_xor(ss, o, 64);
    float inv = 1.0f / fmaxf(sqrtf(ss), 1e-12f);
    if (sub == 0) {
        __half2 h0 = __floats2half2_rn(f0.x * inv, f0.y * inv);
        __half2 h1 = __floats2half2_rn(f1.x * inv, f1.y * inv);
        __half2 h2 = __floats2half2_rn(f2.x * inv, f2.y * inv);
        __half2 h3 = __floats2half2_rn(f3.x * inv, f3.y * inv);
        uint4 pv;
        pv.x = *(unsigned*)&h0; pv.y = *(unsigned*)&h1;
        pv.z = *(unsigned*)&h2; pv.w = *(unsigned*)&h3;
        *(uint4*)(demb + (size_t)row * DIM + l8 * 8) = pv;
    }
}

// ---------------- launch ----------------

extern "C" void kernel_launch(void* const* d_in, const int* in_sizes, int n_in,
                              void* d_out, int out_size, void* d_ws, size_t ws_size,
                              hipStream_t stream) {
    const float* user_table = (const float*)d_in[0];
    const float* item_table = (const float*)d_in[1];
    const int*   u_idx      = (const int*)d_in[2];
    const int*   i_idx      = (const int*)d_in[3];
    const int*   edges      = (const int*)d_in[4];
    const int*   u_nodes    = edges;              // edge_index[0]
    const int*   i_nodes    = edges + NUM_EDGES;  // edge_index[1]
    float*       out        = (float*)d_out;

    // ---- workspace layout (~130 MB) ----
    __half* uH0 = (__half*)d_ws;        // fp16 table copy (25.6 MB)
    __half* uE1 = uH0 + NU64;           // layer-1 user emb
    __half* uE2 = uE1 + NU64;           // layer-2
    __half* uE3 = uE2 + NU64;           // layer-3
    __half* iH0 = uE3 + NU64;           // fp16 item table copy (12.8 MB)
    __half* iE1 = iH0 + NI64;
    __half* iE2 = iE1 + NI64;
    __half* iE3 = iE2 + NI64;

    int* ip     = (int*)(iE3 + NI64);
    int* u_offs = ip;                        // NUM_USERS
    int* i_offs = u_offs + NUM_USERS;        // NUM_ITEMS
    int* u_deg  = i_offs + NUM_ITEMS;        // NUM_USERS
    int* i_deg  = u_deg + NUM_USERS;         // NUM_ITEMS
    int* u_adj  = i_deg + NUM_ITEMS;         // NBU*CAPU (9.6 MB)
    int* i_adj  = u_adj + (size_t)NBU * CAPU;  // NBI*CAPI (9.6 MB)
    int* gcurU  = i_adj + (size_t)NBI * CAPI;  // NBU
    int* gcurI  = gcurU + NBU;               // NBI
    unsigned* stageU = (unsigned*)(gcurI + NBI);      // NBU*CAPU u32 (9.6 MB)
    unsigned* stageI = stageU + (size_t)NBU * CAPU;   // NBI*CAPI u32 (9.6 MB)

    // ---- init: fp16 copies of the tables ----
    {
        int n4 = (int)((NU64 + NI64) / 4);
        convert_kernel<<<(n4 + 255) / 256, 256, 0, stream>>>(
            (const float4*)user_table, (const float4*)item_table,
            (uint2*)uH0, (uint2*)iH0);
    }

    // ---- CSR build v3 ----
    hipMemsetAsync(gcurU, 0, (NBU + NBI) * sizeof(int), stream);

    int nblkA = (NUM_EDGES + EPB - 1) / EPB;
    bucket_scatter<<<nblkA, 256, 0, stream>>>(u_nodes, i_nodes, gcurU, gcurI, stageU, stageI);
    bucket_place<<<NBU + NBI, 1024, 0, stream>>>(gcurU, gcurI, stageU, stageI,
                                                 u_offs, i_offs, u_deg, i_deg, u_adj, i_adj);

    // ---- 3 fused pull layers (fp16 gathers; each layer's emb persisted) ----
    long long waves = (long long)(NUM_USERS + NUM_ITEMS);
    int blocks = (int)((waves * 64 + 255) / 256);
    const __half* uprevs[3] = {uH0, uE1, uE2};
    const __half* iprevs[3] = {iH0, iE1, iE2};
    __half* udsts[3] = {uE1, uE2, uE3};
    __half* idsts[3] = {iE1, iE2, iE3};
    for (int l = 0; l < NUM_LAYERS; ++l) {
        pull_norm_kernel<<<blocks, 256, 0, stream>>>(u_offs, u_deg, u_adj,
                                                     i_offs, i_deg, i_adj,
                                                     uprevs[l], iprevs[l],
                                                     udsts[l], idsts[l]);
    }

    // ---- final dot over sampled rows: (table + e1 + e2 + e3) . (table + e1 + e2 + e3) / 16 ----
    {
        long long tb = (long long)BATCH * 64;
        final_dot_kernel<<<(int)((tb + 255) / 256), 256, 0, stream>>>(
            user_table, item_table, uE1, uE2, uE3, iE1, iE2, iE3, u_idx, i_idx, out);
    }
}

// Round 20
// 465.090 us; speedup vs baseline: 1.0856x; 1.0140x over previous
//
#include <hip/hip_runtime.h>
#include <hip/hip_fp16.h>

#define NUM_USERS 200000
#define NUM_ITEMS 100000
#define DIM 64
#define NUM_EDGES 2000000
#define BATCH 16384
#define NUM_LAYERS 3

#define NU64 ((size_t)NUM_USERS * DIM)
#define NI64 ((size_t)NUM_ITEMS * DIM)

// bucketed CSR: user buckets = 2048-node ranges, item buckets = 1024-node ranges
#define RU_SHIFT 11
#define RI_SHIFT 10
#define NBU 98   // ceil(200000 / 2048)
#define NBI 98   // ceil(100000 / 1024)
#define CAPU 24576  // fixed capacity per bucket (expected ~20480, 28-sigma margin)
#define CAPI 24576
#define EPB 1024    // edges per scatter block
#define VMASK 0x3FFFF  // 18-bit neighbor id (max 200000 < 262144)

// ---------------- init (fp16 table copies) ----------------

__global__ void convert_kernel(const float4* __restrict__ ut, const float4* __restrict__ it,
                               uint2* __restrict__ uH, uint2* __restrict__ iH) {
    int idx = blockIdx.x * blockDim.x + threadIdx.x;
    const int n4u = (int)(NU64 / 4), n4i = (int)(NI64 / 4);
    if (idx < n4u) {
        float4 v = ut[idx];
        __half2 h0 = __floats2half2_rn(v.x, v.y);
        __half2 h1 = __floats2half2_rn(v.z, v.w);
        uint2 p; p.x = *(unsigned*)&h0; p.y = *(unsigned*)&h1;
        uH[idx] = p;
    } else if (idx < n4u + n4i) {
        int k = idx - n4u;
        float4 v = it[k];
        __half2 h0 = __floats2half2_rn(v.x, v.y);
        __half2 h1 = __floats2half2_rn(v.z, v.w);
        uint2 p; p.x = *(unsigned*)&h0; p.y = *(unsigned*)&h1;
        iH[k] = p;
    }
}

// ---------------- final dot: gather table + 3 layer embs at sampled rows ----------------

__global__ void final_dot_kernel(const float* __restrict__ uT, const float* __restrict__ iT,
                                 const __half* __restrict__ uE1, const __half* __restrict__ uE2,
                                 const __half* __restrict__ uE3,
                                 const __half* __restrict__ iE1, const __half* __restrict__ iE2,
                                 const __half* __restrict__ iE3,
                                 const int* __restrict__ u_idx, const int* __restrict__ i_idx,
                                 float* __restrict__ out) {
    int b    = (blockIdx.x * blockDim.x + threadIdx.x) >> 6;
    int lane = threadIdx.x & 63;
    if (b >= BATCH) return;
    int u = u_idx[b];
    int i = i_idx[b];
    size_t uo = (size_t)u * DIM + lane;
    size_t io = (size_t)i * DIM + lane;
    float su = uT[uo] + __half2float(uE1[uo]) + __half2float(uE2[uo]) + __half2float(uE3[uo]);
    float si = iT[io] + __half2float(iE1[io]) + __half2float(iE2[io]) + __half2float(iE3[io]);
    float p = su * si;
    #pragma unroll
    for (int o = 32; o > 0; o >>= 1) p += __shfl_xor(p, o, 64);
    if (lane == 0) out[b] = p * (1.0f / ((NUM_LAYERS + 1) * (NUM_LAYERS + 1)));
}

// ---------------- CSR construction v3 (packed 4B staging records) ----------------

// Pass A: per-wave-replicated LDS binning, fixed-capacity per-bucket staging.
// Record = (node_offset_in_bucket << 18) | neighbor_id.
__global__ void bucket_scatter(const int* __restrict__ un, const int* __restrict__ in_,
                               int* __restrict__ gcurU, int* __restrict__ gcurI,
                               unsigned* __restrict__ stageU, unsigned* __restrict__ stageI) {
    __shared__ int cntU[4][NBU], cntI[4][NBI];
    __shared__ int baseU[4][NBU], baseI[4][NBI];
    int t = threadIdx.x;
    int w = t >> 6;  // wave 0..3
    for (int k = t; k < 4 * NBU; k += 256) ((int*)cntU)[k] = 0;
    for (int k = t; k < 4 * NBI; k += 256) ((int*)cntI)[k] = 0;
    __syncthreads();
    int e0 = blockIdx.x * EPB + t;
    int u[4], it[4], bu[4], bi[4], ru[4], ri[4];
    bool valid[4];
    #pragma unroll
    for (int k = 0; k < 4; ++k) {
        int e = e0 + k * 256;
        valid[k] = (e < NUM_EDGES);
        if (valid[k]) {
            u[k]  = un[e];
            it[k] = in_[e];
            bu[k] = u[k]  >> RU_SHIFT;
            bi[k] = it[k] >> RI_SHIFT;
            ru[k] = atomicAdd(&cntU[w][bu[k]], 1);
            ri[k] = atomicAdd(&cntI[w][bi[k]], 1);
        }
    }
    __syncthreads();
    if (t < NBU) {
        int c0 = cntU[0][t], c1 = cntU[1][t], c2 = cntU[2][t], c3 = cntU[3][t];
        int b = t * CAPU + atomicAdd(&gcurU[t], c0 + c1 + c2 + c3);
        baseU[0][t] = b; baseU[1][t] = b + c0; baseU[2][t] = b + c0 + c1; baseU[3][t] = b + c0 + c1 + c2;
    }
    if (t < NBI) {
        int c0 = cntI[0][t], c1 = cntI[1][t], c2 = cntI[2][t], c3 = cntI[3][t];
        int b = t * CAPI + atomicAdd(&gcurI[t], c0 + c1 + c2 + c3);
        baseI[0][t] = b; baseI[1][t] = b + c0; baseI[2][t] = b + c0 + c1; baseI[3][t] = b + c0 + c1 + c2;
    }
    __syncthreads();
    #pragma unroll
    for (int k = 0; k < 4; ++k) {
        if (valid[k]) {
            stageU[baseU[w][bu[k]] + ru[k]] = ((unsigned)(u[k]  & ((1 << RU_SHIFT) - 1)) << 18) | (unsigned)it[k];
            stageI[baseI[w][bi[k]] + ri[k]] = ((unsigned)(it[k] & ((1 << RI_SHIFT) - 1)) << 18) | (unsigned)u[k];
        }
    }
}

// Pass B: one block per bucket. Per-node counts + LDS prefix scan produce
// offs/deg locally, then place records with LDS cursors.
__global__ void bucket_place(const int* __restrict__ gcurU, const int* __restrict__ gcurI,
                             const unsigned* __restrict__ stageU, const unsigned* __restrict__ stageI,
                             int* __restrict__ u_offs, int* __restrict__ i_offs,
                             int* __restrict__ u_deg, int* __restrict__ i_deg,
                             int* __restrict__ u_adj, int* __restrict__ i_adj) {
    __shared__ int cnt[2048];
    __shared__ int offs_l[2048];
    __shared__ int wsum[1024];
    int b = blockIdx.x, t = threadIdx.x;
    const unsigned* stage; int* adj; int* offs; int* deg; int lo, range, nrec, bbase;
    if (b < NBU) {
        stage = stageU + (size_t)b * CAPU; adj = u_adj; offs = u_offs; deg = u_deg;
        nrec = gcurU[b]; lo = b << RU_SHIFT; bbase = b * CAPU;
        range = NUM_USERS - lo; if (range > 2048) range = 2048;
    } else {
        int bb = b - NBU;
        stage = stageI + (size_t)bb * CAPI; adj = i_adj; offs = i_offs; deg = i_deg;
        nrec = gcurI[bb]; lo = bb << RI_SHIFT; bbase = bb * CAPI;
        range = NUM_ITEMS - lo; if (range > 1024) range = 1024;
    }
    cnt[t] = 0; cnt[t + 1024] = 0;
    __syncthreads();
    for (int r = t; r < nrec; r += 1024) atomicAdd(&cnt[stage[r] >> 18], 1);
    __syncthreads();
    int c0 = cnt[2 * t], c1 = cnt[2 * t + 1];
    int s = c0 + c1;
    wsum[t] = s;
    __syncthreads();
    for (int off = 1; off < 1024; off <<= 1) {
        int v = (t >= off) ? wsum[t - off] : 0;
        __syncthreads();
        wsum[t] += v;
        __syncthreads();
    }
    int excl = wsum[t] - s;  // exclusive prefix of node 2t
    offs_l[2 * t] = excl;
    offs_l[2 * t + 1] = excl + c0;
    if (2 * t < range)     { offs[lo + 2 * t]     = bbase + excl;      deg[lo + 2 * t]     = c0; }
    if (2 * t + 1 < range) { offs[lo + 2 * t + 1] = bbase + excl + c0; deg[lo + 2 * t + 1] = c1; }
    cnt[2 * t] = 0; cnt[2 * t + 1] = 0;   // reuse as placement cursors
    __syncthreads();
    for (int r = t; r < nrec; r += 1024) {
        unsigned rec = stage[r];
        int loc = (int)(rec >> 18);
        int p = atomicAdd(&cnt[loc], 1);
        adj[bbase + offs_l[loc] + p] = (int)(rec & VMASK);
    }
}

// ---------------- fused pull + normalize (8x8 sub-group, uint4 loads, 32-bit offsets) ----------------
// Wave = 8 subs x 8 lanes; sub s handles neighbor j+s; lane loads uint4 = 8 fp16
// dims via uniform-base + 32-bit byte offset (saddr form). fp16 packed accumulate;
// shfl/load never inside divergent branches. f32 norm reduction; fp16 write.
__global__ void pull_norm_kernel(const int* __restrict__ u_offs, const int* __restrict__ u_deg,
                                 const int* __restrict__ u_adj,
                                 const int* __restrict__ i_offs, const int* __restrict__ i_deg,
                                 const int* __restrict__ i_adj,
                                 const __half* __restrict__ uprev, const __half* __restrict__ iprev,
                                 __half* __restrict__ unew, __half* __restrict__ inew) {
    int w    = (blockIdx.x * blockDim.x + threadIdx.x) >> 6;
    int lane = threadIdx.x & 63;
    int sub  = lane >> 3;   // 0..7
    unsigned l8b = (unsigned)(lane & 7) << 4;   // byte offset of this lane's 16B chunk
    const int* offs; const int* deg; const int* adj; const char* src; __half* demb; int row;
    if (w < NUM_USERS) {
        row = w; offs = u_offs; deg = u_deg; adj = u_adj; src = (const char*)iprev; demb = unew;
    } else {
        row = w - NUM_USERS;
        if (row >= NUM_ITEMS) return;
        offs = i_offs; deg = i_deg; adj = i_adj; src = (const char*)uprev; demb = inew;
    }
    int start = offs[row];
    int cnt   = deg[row];
    const char* adjb = (const char*)adj;
    __half2 z = __floats2half2_rn(0.0f, 0.0f);
    __half2 aA0 = z, aA1 = z, aA2 = z, aA3 = z;   // bank A
    __half2 aB0 = z, aB1 = z, aB2 = z, aB3 = z;   // bank B
    for (int base = 0; base < cnt; base += 64) {
        int rem = cnt - base;
        if (rem > 64) rem = 64;
        unsigned ioff = ((unsigned)(start + base + lane)) << 2;   // 32-bit byte offset
        int idx = (lane < rem) ? *(const int*)(adjb + ioff) : 0;
        int j = 0;
        // 16 neighbors per iter: 2 independent 16B loads per lane
        for (; j + 16 <= rem; j += 16) {
            int nbA = __shfl(idx, j + sub, 64);
            int nbB = __shfl(idx, j + 8 + sub, 64);
            uint4 vA = *(const uint4*)(src + (((unsigned)nbA << 7) + l8b));
            uint4 vB = *(const uint4*)(src + (((unsigned)nbB << 7) + l8b));
            aA0 = __hadd2(aA0, *(const __half2*)&vA.x);
            aA1 = __hadd2(aA1, *(const __half2*)&vA.y);
            aA2 = __hadd2(aA2, *(const __half2*)&vA.z);
            aA3 = __hadd2(aA3, *(const __half2*)&vA.w);
            aB0 = __hadd2(aB0, *(const __half2*)&vB.x);
            aB1 = __hadd2(aB1, *(const __half2*)&vB.y);
            aB2 = __hadd2(aB2, *(const __half2*)&vB.z);
            aB3 = __hadd2(aB3, *(const __half2*)&vB.w);
        }
        // tail rounds of 8: shfl+load unconditional, adds predicated
        for (; j < rem; j += 8) {
            int jj = j + sub;                 // <= 63 always (j <= 56, sub <= 7)
            int nb = __shfl(idx, jj, 64);     // idx[jj] == 0 for jj >= rem (safe row 0)
            uint4 v = *(const uint4*)(src + (((unsigned)nb << 7) + l8b));
            if (jj < rem) {
                aA0 = __hadd2(aA0, *(const __half2*)&v.x);
                aA1 = __hadd2(aA1, *(const __half2*)&v.y);
                aA2 = __hadd2(aA2, *(const __half2*)&v.z);
                aA3 = __hadd2(aA3, *(const __half2*)&v.w);
            }
        }
    }
    // merge banks
    aA0 = __hadd2(aA0, aB0);
    aA1 = __hadd2(aA1, aB1);
    aA2 = __hadd2(aA2, aB2);
    aA3 = __hadd2(aA3, aB3);
    // merge the 8 sub partials (lanes differing in bits 3,4,5 hold same dims)
    #pragma unroll
    for (int o = 8; o <= 32; o <<= 1) {
        int t0 = __shfl_xor(*(int*)&aA0, o, 64);
        int t1 = __shfl_xor(*(int*)&aA1, o, 64);
        int t2 = __shfl_xor(*(int*)&aA2, o, 64);
        int t3 = __shfl_xor(*(int*)&aA3, o, 64);
        aA0 = __hadd2(aA0, *(__half2*)&t0);
        aA1 = __hadd2(aA1, *(__half2*)&t1);
        aA2 = __hadd2(aA2, *(__half2*)&t2);
        aA3 = __hadd2(aA3, *(__half2*)&t3);
    }
    // f32 norm over the wave's 64 dims
    float2 f0 = __half22float2(aA0);
    float2 f1 = __half22float2(aA1);
    float2 f2 = __half22float2(aA2);
    float2 f3 = __half22float2(aA3);
    float ss = f0.x * f0.x + f0.y * f0.y + f1.x * f1.x + f1.y * f1.y
             + f2.x * f2.x + f2.y * f2.y + f3.x * f3.x + f3.y * f3.y;
    #pragma unroll
    for (int o = 4; o > 0; o >>= 1) ss += __shfl_xor(ss, o, 64);
    float inv = 1.0f / fmaxf(sqrtf(ss), 1e-12f);
    if (sub == 0) {
        __half2 h0 = __floats2half2_rn(f0.x * inv, f0.y * inv);
        __half2 h1 = __floats2half2_rn(f1.x * inv, f1.y * inv);
        __half2 h2 = __floats2half2_rn(f2.x * inv, f2.y * inv);
        __half2 h3 = __floats2half2_rn(f3.x * inv, f3.y * inv);
        uint4 pv;
        pv.x = *(unsigned*)&h0; pv.y = *(unsigned*)&h1;
        pv.z = *(unsigned*)&h2; pv.w = *(unsigned*)&h3;
        *(uint4*)((char*)demb + (((unsigned)row << 7) + l8b)) = pv;
    }
}

// ---------------- launch ----------------

extern "C" void kernel_launch(void* const* d_in, const int* in_sizes, int n_in,
                              void* d_out, int out_size, void* d_ws, size_t ws_size,
                              hipStream_t stream) {
    const float* user_table = (const float*)d_in[0];
    const float* item_table = (const float*)d_in[1];
    const int*   u_idx      = (const int*)d_in[2];
    const int*   i_idx      = (const int*)d_in[3];
    const int*   edges      = (const int*)d_in[4];
    const int*   u_nodes    = edges;              // edge_index[0]
    const int*   i_nodes    = edges + NUM_EDGES;  // edge_index[1]
    float*       out        = (float*)d_out;

    // ---- workspace layout (~130 MB) ----
    __half* uH0 = (__half*)d_ws;        // fp16 table copy (25.6 MB)
    __half* uE1 = uH0 + NU64;           // layer-1 user emb
    __half* uE2 = uE1 + NU64;           // layer-2
    __half* uE3 = uE2 + NU64;           // layer-3
    __half* iH0 = uE3 + NU64;           // fp16 item table copy (12.8 MB)
    __half* iE1 = iH0 + NI64;
    __half* iE2 = iE1 + NI64;
    __half* iE3 = iE2 + NI64;

    int* ip     = (int*)(iE3 + NI64);
    int* u_offs = ip;                        // NUM_USERS
    int* i_offs = u_offs + NUM_USERS;        // NUM_ITEMS
    int* u_deg  = i_offs + NUM_ITEMS;        // NUM_USERS
    int* i_deg  = u_deg + NUM_USERS;         // NUM_ITEMS
    int* u_adj  = i_deg + NUM_ITEMS;         // NBU*CAPU (9.6 MB)
    int* i_adj  = u_adj + (size_t)NBU * CAPU;  // NBI*CAPI (9.6 MB)
    int* gcurU  = i_adj + (size_t)NBI * CAPI;  // NBU
    int* gcurI  = gcurU + NBU;               // NBI
    unsigned* stageU = (unsigned*)(gcurI + NBI);      // NBU*CAPU u32 (9.6 MB)
    unsigned* stageI = stageU + (size_t)NBU * CAPU;   // NBI*CAPI u32 (9.6 MB)

    // ---- init: fp16 copies of the tables ----
    {
        int n4 = (int)((NU64 + NI64) / 4);
        convert_kernel<<<(n4 + 255) / 256, 256, 0, stream>>>(
            (const float4*)user_table, (const float4*)item_table,
            (uint2*)uH0, (uint2*)iH0);
    }

    // ---- CSR build v3 ----
    hipMemsetAsync(gcurU, 0, (NBU + NBI) * sizeof(int), stream);

    int nblkA = (NUM_EDGES + EPB - 1) / EPB;
    bucket_scatter<<<nblkA, 256, 0, stream>>>(u_nodes, i_nodes, gcurU, gcurI, stageU, stageI);
    bucket_place<<<NBU + NBI, 1024, 0, stream>>>(gcurU, gcurI, stageU, stageI,
                                                 u_offs, i_offs, u_deg, i_deg, u_adj, i_adj);

    // ---- 3 fused pull layers (fp16 gathers; each layer's emb persisted) ----
    long long waves = (long long)(NUM_USERS + NUM_ITEMS);
    int blocks = (int)((waves * 64 + 255) / 256);
    const __half* uprevs[3] = {uH0, uE1, uE2};
    const __half* iprevs[3] = {iH0, iE1, iE2};
    __half* udsts[3] = {uE1, uE2, uE3};
    __half* idsts[3] = {iE1, iE2, iE3};
    for (int l = 0; l < NUM_LAYERS; ++l) {
        pull_norm_kernel<<<blocks, 256, 0, stream>>>(u_offs, u_deg, u_adj,
                                                     i_offs, i_deg, i_adj,
                                                     uprevs[l], iprevs[l],
                                                     udsts[l], idsts[l]);
    }

    // ---- final dot over sampled rows: (table + e1 + e2 + e3) . (table + e1 + e2 + e3) / 16 ----
    {
        long long tb = (long long)BATCH * 64;
        final_dot_kernel<<<(int)((tb + 255) / 256), 256, 0, stream>>>(
            user_table, item_table, uE1, uE2, uE3, iE1, iE2, iE3, u_idx, i_idx, out);
    }
}